// Round 2
// baseline (1055.468 us; speedup 1.0000x reference)
//
#include <hip/hip_runtime.h>
#include <hip/hip_bf16.h>
#include <math.h>

#define T_TOKENS 8192
#define DIMK     1024
#define INTER    2048
#define NE       8
#define CAP      17408   // 2*T + NE*128

typedef __attribute__((ext_vector_type(8))) short bf16x8;
typedef __attribute__((ext_vector_type(8))) unsigned short u16x8;
typedef __attribute__((ext_vector_type(4))) float f32x4;

__device__ __forceinline__ unsigned short f2bf(float f) {
  unsigned int u = __float_as_uint(f);
  unsigned int r = 0x7FFFu + ((u >> 16) & 1u);
  return (unsigned short)((u + r) >> 16);
}
__device__ __forceinline__ float silu_f(float v) { return v / (1.0f + expf(-v)); }

__device__ __forceinline__ u16x8 cvt8(float4 a, float4 b) {
  u16x8 r;
  r[0] = f2bf(a.x); r[1] = f2bf(a.y); r[2] = f2bf(a.z); r[3] = f2bf(a.w);
  r[4] = f2bf(b.x); r[5] = f2bf(b.y); r[6] = f2bf(b.z); r[7] = f2bf(b.w);
  return r;
}

__device__ __forceinline__ void gl_lds16(const void* g, void* l) {
  __builtin_amdgcn_global_load_lds(
      (const __attribute__((address_space(1))) void*)g,
      (__attribute__((address_space(3))) void*)l, 16, 0, 0);
}

__device__ __forceinline__ bool find_expert(const int* cnt, int p0, int& eSel,
                                            int& realEnd) {
  int base = 0;
  for (int i = 0; i < NE; i++) {
    int c = cnt[i];
    int pad = (c + 127) & ~127;
    if (p0 < base + pad) { eSel = i; realEnd = base + c; return p0 < base + c; }
    base += pad;
  }
  return false;
}

// ---------- init ----------
__global__ void init_kernel(int* __restrict__ cnt, int* __restrict__ fill) {
  int i = threadIdx.x;
  if (i < NE) { cnt[i] = 0; fill[i] = 0; }
}

// ---------- fp32 -> bf16 ----------
__global__ __launch_bounds__(256) void cvt_kernel(const float* __restrict__ s,
                                                  unsigned short* __restrict__ d,
                                                  int n) {
  int i = (blockIdx.x * 256 + threadIdx.x) * 8;
  if (i >= n) return;
  float4 a = *(const float4*)(s + i);
  float4 b = *(const float4*)(s + i + 4);
  *(u16x8*)(d + i) = cvt8(a, b);
}

// ---------- gate ----------
__global__ __launch_bounds__(256) void gate_kernel(
    const float* __restrict__ x, const float* __restrict__ gw,
    const float* __restrict__ gb, int* __restrict__ cnt,
    int* __restrict__ topk_idx, float* __restrict__ topk_w) {
  const int wave = threadIdx.x >> 6;
  const int lane = threadIdx.x & 63;
  const int t = blockIdx.x * 4 + wave;
  if (t >= T_TOKENS) return;
  const float* xt = x + (size_t)t * DIMK;

  float p[NE];
#pragma unroll
  for (int e = 0; e < NE; e++) p[e] = 0.0f;
  for (int d = lane; d < DIMK; d += 64) {
    float xv = xt[d];
#pragma unroll
    for (int e = 0; e < NE; e++) p[e] += xv * gw[e * DIMK + d];
  }
#pragma unroll
  for (int e = 0; e < NE; e++) {
#pragma unroll
    for (int off = 32; off > 0; off >>= 1) p[e] += __shfl_xor(p[e], off, 64);
  }
  if (lane == 0) {
    float m = p[0];
#pragma unroll
    for (int e = 1; e < NE; e++) m = fmaxf(m, p[e]);
    float s[NE]; float den = 0.0f;
#pragma unroll
    for (int e = 0; e < NE; e++) { s[e] = expf(p[e] - m); den += s[e]; }
    float inv = 1.0f / den;
    float sc[NE], bi[NE];
#pragma unroll
    for (int e = 0; e < NE; e++) { sc[e] = s[e] * inv; bi[e] = sc[e] + gb[e]; }
    int i0 = 0; float b0 = bi[0];
#pragma unroll
    for (int e = 1; e < NE; e++) if (bi[e] > b0) { b0 = bi[e]; i0 = e; }
    int i1 = -1; float b1 = -1e30f;
#pragma unroll
    for (int e = 0; e < NE; e++) if (e != i0 && bi[e] > b1) { b1 = bi[e]; i1 = e; }
    topk_idx[t * 2 + 0] = i0;
    topk_idx[t * 2 + 1] = i1;
    topk_w[t * 2 + 0] = sc[i0];
    topk_w[t * 2 + 1] = sc[i1];
    atomicAdd(&cnt[i0], 1);
    atomicAdd(&cnt[i1], 1);
  }
}

// ---------- scatter (also records token -> pair-slot inverse map) ----------
__global__ __launch_bounds__(256) void scatter_kernel(
    const int* __restrict__ cnt, int* __restrict__ fill,
    const int* __restrict__ topk_idx, const float* __restrict__ topk_w,
    int* __restrict__ pair_tok, float* __restrict__ pair_w,
    int* __restrict__ pos) {
  int t = blockIdx.x * blockDim.x + threadIdx.x;
  if (t >= T_TOKENS) return;
  int offp[NE];
  int o = 0;
#pragma unroll
  for (int e = 0; e < NE; e++) { offp[e] = o; o += (cnt[e] + 127) & ~127; }
#pragma unroll
  for (int k = 0; k < 2; k++) {
    int e = topk_idx[t * 2 + k];
    int po = atomicAdd(&fill[e], 1);
    int p = offp[e] + po;
    pair_tok[p] = t;
    pair_w[p] = topk_w[t * 2 + k];
    pos[t * 2 + k] = p;
  }
}

// ---------- GEMM 1: H = silu(A@W1^T)*(A@W3^T) ----------
// block tile: 128M x 64N; 4 waves; 2-phase double-buffered LDS pipeline.
// LDS slot swizzle: 16B slot s at row r holds global slot s ^ f(r),
// f(r) = (r&3)^((r>>2)&3) -> ds_read_b128 conflicts drop 8-way -> 2-way (free).
template <bool ROUTED, bool BBF16>
__global__ __launch_bounds__(256) void h_mfma(
    const unsigned short* __restrict__ xb, const void* __restrict__ w1p,
    const void* __restrict__ w3p, const int* __restrict__ cnt,
    const int* __restrict__ pair_tok, unsigned short* __restrict__ H) {
  const int p0 = blockIdx.y * 128;
  int realEnd = T_TOKENS, eSel = 0;
  if (ROUTED) {
    if (!find_expert(cnt, p0, eSel, realEnd)) return;
  }
  const size_t wOff = (size_t)eSel * INTER * DIMK;

  const int tid = threadIdx.x;
  const int lane = tid & 63;
  const int wv = tid >> 6;
  const int wm = (wv & 1) * 64, wn = (wv >> 1) * 32;
  const int lm = lane & 15, quad = lane >> 4;
  const int n0 = blockIdx.x * 64;

  const int srow = tid >> 2;
  const int fsr = (srow & 3) ^ ((srow >> 2) & 3);
  const int skg = (((tid & 3) ^ fsr)) * 8;   // swizzled source k-group (elements)
  const int rdS = (quad ^ ((lane & 3) ^ ((lane >> 2) & 3))) * 8;  // swizzled read slot

  int pa0 = p0 + srow, pa1 = p0 + srow + 64;
  int tok0, tok1;
  if (ROUTED) {
    tok0 = pair_tok[pa0 < realEnd ? pa0 : realEnd - 1];
    tok1 = pair_tok[pa1 < realEnd ? pa1 : realEnd - 1];
  } else { tok0 = pa0; tok1 = pa1; }
  const unsigned short* aSrc0 = xb + (size_t)tok0 * DIMK + skg;
  const unsigned short* aSrc1 = xb + (size_t)tok1 * DIMK + skg;

  const unsigned short* b1Src = nullptr; const unsigned short* b3Src = nullptr;
  const float* b1f32 = nullptr; const float* b3f32 = nullptr;
  if constexpr (BBF16) {
    b1Src = (const unsigned short*)w1p + wOff + (size_t)(n0 + srow) * DIMK + skg;
    b3Src = (const unsigned short*)w3p + wOff + (size_t)(n0 + srow) * DIMK + skg;
  } else {
    b1f32 = (const float*)w1p + wOff + (size_t)(n0 + srow) * DIMK + skg;
    b3f32 = (const float*)w3p + wOff + (size_t)(n0 + srow) * DIMK + skg;
  }

  __shared__ alignas(16) unsigned short As[2][128 * 32];
  __shared__ alignas(16) unsigned short B1s[2][64 * 32];
  __shared__ alignas(16) unsigned short B3s[2][64 * 32];

  f32x4 acc1[4][2] = {};
  f32x4 acc3[4][2] = {};

  auto compute = [&](int b) {
    bf16x8 af[4], b1r[2], b3r[2];
#pragma unroll
    for (int mi = 0; mi < 4; mi++)
      af[mi] = *(const bf16x8*)&As[b][(wm + mi * 16 + lm) * 32 + rdS];
#pragma unroll
    for (int ni = 0; ni < 2; ni++) {
      b1r[ni] = *(const bf16x8*)&B1s[b][(wn + ni * 16 + lm) * 32 + rdS];
      b3r[ni] = *(const bf16x8*)&B3s[b][(wn + ni * 16 + lm) * 32 + rdS];
    }
#pragma unroll
    for (int mi = 0; mi < 4; mi++) {
#pragma unroll
      for (int ni = 0; ni < 2; ni++) {
        acc1[mi][ni] = __builtin_amdgcn_mfma_f32_16x16x32_bf16(
            af[mi], b1r[ni], acc1[mi][ni], 0, 0, 0);
        acc3[mi][ni] = __builtin_amdgcn_mfma_f32_16x16x32_bf16(
            af[mi], b3r[ni], acc3[mi][ni], 0, 0, 0);
      }
    }
  };

  if constexpr (BBF16) {
    // prologue: stage k-tile 0 into buf 0
    gl_lds16(aSrc0, &As[0][tid * 8]);
    gl_lds16(aSrc1, &As[0][2048 + tid * 8]);
    gl_lds16(b1Src, &B1s[0][tid * 8]);
    gl_lds16(b3Src, &B3s[0][tid * 8]);
    __syncthreads();
    int cur = 0;
    for (int k0 = 32; k0 < DIMK; k0 += 32) {
      const int nxt = cur ^ 1;
      // issue next-tile loads BEFORE compute; barrier drains them at iter end
      gl_lds16(aSrc0 + k0, &As[nxt][tid * 8]);
      gl_lds16(aSrc1 + k0, &As[nxt][2048 + tid * 8]);
      gl_lds16(b1Src + k0, &B1s[nxt][tid * 8]);
      gl_lds16(b3Src + k0, &B3s[nxt][tid * 8]);
      compute(cur);
      __syncthreads();
      cur = nxt;
    }
    compute(cur);  // epilogue tile, no prefetch
  } else {
    for (int k0 = 0; k0 < DIMK; k0 += 32) {
      const float4* p1 = (const float4*)(b1f32 + k0);
      const float4* p3 = (const float4*)(b3f32 + k0);
      float4 a1 = p1[0], c1 = p1[1], a3 = p3[0], c3 = p3[1];
      u16x8 b1v = cvt8(a1, c1);
      u16x8 b3v = cvt8(a3, c3);
      __syncthreads();
      gl_lds16(aSrc0 + k0, &As[0][tid * 8]);
      gl_lds16(aSrc1 + k0, &As[0][2048 + tid * 8]);
      *(u16x8*)&B1s[0][tid * 8] = b1v;
      *(u16x8*)&B3s[0][tid * 8] = b3v;
      __syncthreads();
      compute(0);
    }
  }

#pragma unroll
  for (int mi = 0; mi < 4; mi++) {
#pragma unroll
    for (int r = 0; r < 4; r++) {
      int row = p0 + wm + mi * 16 + quad * 4 + r;
      if (!ROUTED || row < realEnd) {
        unsigned short* hrow = H + (size_t)row * INTER + n0 + wn + lm;
#pragma unroll
        for (int ni = 0; ni < 2; ni++) {
          float v = silu_f(acc1[mi][ni][r]) * acc3[mi][ni][r];
          hrow[ni * 16] = f2bf(v);
        }
      }
    }
  }
}

// ---------- GEMM 2: out = H @ W2^T (128x128 block, 64x64/wave) ----------
// SCRATCH: write raw fp32 results to rout[CAP][DIMK] (no atomics); a combine
// kernel applies routing weights. Else: legacy atomicAdd path.
template <bool ROUTED, bool BBF16, bool SCRATCH>
__global__ __launch_bounds__(256) void out_mfma(
    const unsigned short* __restrict__ H, const void* __restrict__ w2p,
    const int* __restrict__ cnt, const int* __restrict__ pair_tok,
    const float* __restrict__ pair_w, float* __restrict__ out,
    float* __restrict__ rout) {
  const int p0 = blockIdx.y * 128;
  int realEnd = T_TOKENS, eSel = 0;
  if (ROUTED) {
    if (!find_expert(cnt, p0, eSel, realEnd)) return;
  }
  const size_t wOff = (size_t)eSel * DIMK * INTER;

  const int tid = threadIdx.x;
  const int lane = tid & 63;
  const int wv = tid >> 6;
  const int wm = (wv & 1) * 64, wn = (wv >> 1) * 64;
  const int lm = lane & 15, quad = lane >> 4;
  const int n0 = blockIdx.x * 128;

  const int srow = tid >> 2;
  const int fsr = (srow & 3) ^ ((srow >> 2) & 3);
  const int skg = (((tid & 3) ^ fsr)) * 8;
  const int rdS = (quad ^ ((lane & 3) ^ ((lane >> 2) & 3))) * 8;

  const unsigned short* aSrc0 = H + (size_t)(p0 + srow) * INTER + skg;
  const unsigned short* aSrc1 = H + (size_t)(p0 + srow + 64) * INTER + skg;

  const unsigned short* bSrc0 = nullptr; const unsigned short* bSrc1 = nullptr;
  const float* bF0 = nullptr; const float* bF1 = nullptr;
  if constexpr (BBF16) {
    bSrc0 = (const unsigned short*)w2p + wOff + (size_t)(n0 + srow) * INTER + skg;
    bSrc1 = (const unsigned short*)w2p + wOff + (size_t)(n0 + srow + 64) * INTER + skg;
  } else {
    bF0 = (const float*)w2p + wOff + (size_t)(n0 + srow) * INTER + skg;
    bF1 = (const float*)w2p + wOff + (size_t)(n0 + srow + 64) * INTER + skg;
  }

  __shared__ alignas(16) unsigned short As[2][128 * 32];
  __shared__ alignas(16) unsigned short Bs[2][128 * 32];

  f32x4 acc[4][4] = {};

  auto compute = [&](int b) {
    bf16x8 af[4], bf[4];
#pragma unroll
    for (int mi = 0; mi < 4; mi++)
      af[mi] = *(const bf16x8*)&As[b][(wm + mi * 16 + lm) * 32 + rdS];
#pragma unroll
    for (int ni = 0; ni < 4; ni++)
      bf[ni] = *(const bf16x8*)&Bs[b][(wn + ni * 16 + lm) * 32 + rdS];
#pragma unroll
    for (int mi = 0; mi < 4; mi++) {
#pragma unroll
      for (int ni = 0; ni < 4; ni++) {
        acc[mi][ni] = __builtin_amdgcn_mfma_f32_16x16x32_bf16(
            af[mi], bf[ni], acc[mi][ni], 0, 0, 0);
      }
    }
  };

  if constexpr (BBF16) {
    gl_lds16(aSrc0, &As[0][tid * 8]);
    gl_lds16(aSrc1, &As[0][2048 + tid * 8]);
    gl_lds16(bSrc0, &Bs[0][tid * 8]);
    gl_lds16(bSrc1, &Bs[0][2048 + tid * 8]);
    __syncthreads();
    int cur = 0;
    for (int k0 = 32; k0 < INTER; k0 += 32) {
      const int nxt = cur ^ 1;
      gl_lds16(aSrc0 + k0, &As[nxt][tid * 8]);
      gl_lds16(aSrc1 + k0, &As[nxt][2048 + tid * 8]);
      gl_lds16(bSrc0 + k0, &Bs[nxt][tid * 8]);
      gl_lds16(bSrc1 + k0, &Bs[nxt][2048 + tid * 8]);
      compute(cur);
      __syncthreads();
      cur = nxt;
    }
    compute(cur);
  } else {
    for (int k0 = 0; k0 < INTER; k0 += 32) {
      const float4* q0 = (const float4*)(bF0 + k0);
      const float4* q1 = (const float4*)(bF1 + k0);
      float4 a0 = q0[0], c0 = q0[1], a1 = q1[0], c1 = q1[1];
      u16x8 bv0 = cvt8(a0, c0);
      u16x8 bv1 = cvt8(a1, c1);
      __syncthreads();
      gl_lds16(aSrc0 + k0, &As[0][tid * 8]);
      gl_lds16(aSrc1 + k0, &As[0][2048 + tid * 8]);
      *(u16x8*)&Bs[0][tid * 8] = bv0;
      *(u16x8*)&Bs[0][2048 + tid * 8] = bv1;
      __syncthreads();
      compute(0);
    }
  }

#pragma unroll
  for (int mi = 0; mi < 4; mi++) {
#pragma unroll
    for (int r = 0; r < 4; r++) {
      int row = p0 + wm + mi * 16 + quad * 4 + r;
      if constexpr (!ROUTED) {
        float* orow = out + (size_t)row * DIMK + n0 + wn + lm;
#pragma unroll
        for (int ni = 0; ni < 4; ni++) orow[ni * 16] = acc[mi][ni][r];
      } else {
        if (row < realEnd) {
          if constexpr (SCRATCH) {
            float* rrow = rout + (size_t)row * DIMK + n0 + wn + lm;
#pragma unroll
            for (int ni = 0; ni < 4; ni++) rrow[ni * 16] = acc[mi][ni][r];
          } else {
            int tok = pair_tok[row];
            float wgt = pair_w[row];
            float* orow = out + (size_t)tok * DIMK + n0 + wn + lm;
#pragma unroll
            for (int ni = 0; ni < 4; ni++)
              atomicAdd(&orow[ni * 16], acc[mi][ni][r] * wgt);
          }
        }
      }
    }
  }
}

// ---------- combine: out[t] = shared_out[t] + w0*R[p0] + w1*R[p1] ----------
__global__ __launch_bounds__(256) void combine_kernel(
    const float* __restrict__ rt, const int* __restrict__ pos,
    const float* __restrict__ topk_w, float* __restrict__ out) {
  const int t = blockIdx.x;
  const int c = threadIdx.x * 4;
  const int q0 = pos[t * 2 + 0], q1 = pos[t * 2 + 1];
  const float w0 = topk_w[t * 2 + 0], w1 = topk_w[t * 2 + 1];
  float4 o = *(const float4*)(out + (size_t)t * DIMK + c);
  float4 a = *(const float4*)(rt + (size_t)q0 * DIMK + c);
  float4 b = *(const float4*)(rt + (size_t)q1 * DIMK + c);
  o.x += w0 * a.x + w1 * b.x;
  o.y += w0 * a.y + w1 * b.y;
  o.z += w0 * a.z + w1 * b.z;
  o.w += w0 * a.w + w1 * b.w;
  *(float4*)(out + (size_t)t * DIMK + c) = o;
}

// ---------- launch ----------
extern "C" void kernel_launch(void* const* d_in, const int* in_sizes, int n_in,
                              void* d_out, int out_size, void* d_ws, size_t ws_size,
                              hipStream_t stream) {
  const float* x   = (const float*)d_in[0];
  const float* gw  = (const float*)d_in[1];
  const float* gb  = (const float*)d_in[2];
  const float* w1  = (const float*)d_in[3];
  const float* w2  = (const float*)d_in[4];
  const float* w3  = (const float*)d_in[5];
  const float* sw1 = (const float*)d_in[6];
  const float* sw2 = (const float*)d_in[7];
  const float* sw3 = (const float*)d_in[8];
  float* out = (float*)d_out;
  (void)in_sizes; (void)n_in; (void)out_size;

  char* ws = (char*)d_ws;
  int* cnt = (int*)ws;
  int* fill = cnt + 8;
  int* topk_idx = fill + 8;
  float* topk_w = (float*)(topk_idx + 2 * T_TOKENS);
  int* pos = (int*)(topk_w + 2 * T_TOKENS);
  int* pair_tok = pos + 2 * T_TOKENS;
  float* pair_w = (float*)(pair_tok + CAP);
  size_t off = (size_t)((char*)(pair_w + CAP) - ws);
  off = (off + 255) & ~(size_t)255;
  unsigned short* H = (unsigned short*)(ws + off);
  off += (size_t)CAP * INTER * 2;
  unsigned short* xb = (unsigned short*)(ws + off);
  off += (size_t)T_TOKENS * DIMK * 2;

  const size_t nRW = (size_t)NE * INTER * DIMK;   // 16.8M elems per routed matrix
  const size_t nSW = (size_t)INTER * DIMK;        // 2.1M elems per shared matrix
  const size_t avail = (ws_size > off) ? ws_size - off : 0;
  const size_t needR = (size_t)CAP * DIMK * 4;    // 71.3 MB routed-out scratch
  const size_t needA = (3 * nRW + 3 * nSW) * 2;   // 113.2 MB all-distinct bf16
  const size_t needB = 2 * nRW * 2;               // 67.1 MB time-multiplexed

  bool USE_R = false, TIER_A = false, TIER_B = false;
  if (avail >= needR + needA)      { USE_R = true; TIER_A = true; }
  else if (avail >= needR + needB) { USE_R = true; TIER_B = true; }
  else if (avail >= needA)         { TIER_A = true; }
  else if (avail >= needB)         { TIER_B = true; }

  float* rt = nullptr;
  if (USE_R) { rt = (float*)(ws + off); off += needR; }

  unsigned short *w1b, *w3b, *w2b, *sw1b, *sw3b, *sw2b;
  if (TIER_A) {
    unsigned short* Rg = (unsigned short*)(ws + off);
    w1b = Rg;            w3b = Rg + nRW;      w2b = Rg + 2 * nRW;
    sw1b = Rg + 3 * nRW; sw3b = sw1b + nSW;   sw2b = sw1b + 2 * nSW;
  } else if (TIER_B) {
    unsigned short* Rg = (unsigned short*)(ws + off);
    w1b = Rg; w3b = Rg + nRW;   // w1+w3 phase
    w2b = Rg;                   // reuses after routed h
    sw1b = Rg; sw3b = Rg + nSW; // shared phase
    sw2b = Rg;                  // reuses after shared h
  } else {
    w1b = w3b = w2b = sw1b = sw3b = sw2b = nullptr;
  }

  init_kernel<<<1, 64, 0, stream>>>(cnt, fill);
  cvt_kernel<<<(T_TOKENS * DIMK) / 2048, 256, 0, stream>>>(x, xb, T_TOKENS * DIMK);
  gate_kernel<<<T_TOKENS / 4, 256, 0, stream>>>(x, gw, gb, cnt, topk_idx, topk_w);
  scatter_kernel<<<T_TOKENS / 256, 256, 0, stream>>>(cnt, fill, topk_idx, topk_w,
                                                     pair_tok, pair_w, pos);

  if (TIER_A || TIER_B) {
    // shared expert
    cvt_kernel<<<(int)(nSW / 2048), 256, 0, stream>>>(sw1, sw1b, (int)nSW);
    cvt_kernel<<<(int)(nSW / 2048), 256, 0, stream>>>(sw3, sw3b, (int)nSW);
    h_mfma<false, true><<<dim3(INTER / 64, T_TOKENS / 128), 256, 0, stream>>>(
        xb, sw1b, sw3b, nullptr, nullptr, H);
    cvt_kernel<<<(int)(nSW / 2048), 256, 0, stream>>>(sw2, sw2b, (int)nSW);
    out_mfma<false, true, false><<<dim3(DIMK / 128, T_TOKENS / 128), 256, 0, stream>>>(
        H, sw2b, nullptr, nullptr, nullptr, out, nullptr);
    // routed experts
    cvt_kernel<<<(int)(nRW / 2048), 256, 0, stream>>>(w1, w1b, (int)nRW);
    cvt_kernel<<<(int)(nRW / 2048), 256, 0, stream>>>(w3, w3b, (int)nRW);
    h_mfma<true, true><<<dim3(INTER / 64, CAP / 128), 256, 0, stream>>>(
        xb, w1b, w3b, cnt, pair_tok, H);
    cvt_kernel<<<(int)(nRW / 2048), 256, 0, stream>>>(w2, w2b, (int)nRW);
    if (USE_R) {
      out_mfma<true, true, true><<<dim3(DIMK / 128, CAP / 128), 256, 0, stream>>>(
          H, w2b, cnt, pair_tok, pair_w, out, rt);
      combine_kernel<<<T_TOKENS, 256, 0, stream>>>(rt, pos, topk_w, out);
    } else {
      out_mfma<true, true, false><<<dim3(DIMK / 128, CAP / 128), 256, 0, stream>>>(
          H, w2b, cnt, pair_tok, pair_w, out, nullptr);
    }
  } else {
    h_mfma<false, false><<<dim3(INTER / 64, T_TOKENS / 128), 256, 0, stream>>>(
        xb, sw1, sw3, nullptr, nullptr, H);
    out_mfma<false, false, false><<<dim3(DIMK / 128, T_TOKENS / 128), 256, 0, stream>>>(
        H, sw2, nullptr, nullptr, nullptr, out, nullptr);
    h_mfma<true, false><<<dim3(INTER / 64, CAP / 128), 256, 0, stream>>>(
        xb, w1, w3, cnt, pair_tok, H);
    out_mfma<true, false, false><<<dim3(DIMK / 128, CAP / 128), 256, 0, stream>>>(
        H, w2, cnt, pair_tok, pair_w, out, nullptr);
  }
}

// Round 4
// 1040.212 us; speedup vs baseline: 1.0147x; 1.0147x over previous
//
#include <hip/hip_runtime.h>
#include <hip/hip_bf16.h>
#include <math.h>

#define T_TOKENS 8192
#define DIMK     1024
#define INTER    2048
#define NE       8
#define NE9      9       // 8 routed + 1 shared (expert id 8)
#define CAP9     25600   // 2*T + 8*128 (routed padded) + T (shared)

typedef __attribute__((ext_vector_type(8))) short bf16x8;
typedef __attribute__((ext_vector_type(8))) unsigned short u16x8;
typedef __attribute__((ext_vector_type(4))) float f32x4;

#define VM_WAIT(N) asm volatile("s_waitcnt vmcnt(" #N ")" ::: "memory")
#define SCHED_FENCE() __builtin_amdgcn_sched_barrier(0)

__device__ __forceinline__ unsigned short f2bf(float f) {
  unsigned int u = __float_as_uint(f);
  unsigned int r = 0x7FFFu + ((u >> 16) & 1u);
  return (unsigned short)((u + r) >> 16);
}
__device__ __forceinline__ float silu_f(float v) { return v / (1.0f + expf(-v)); }

__device__ __forceinline__ u16x8 cvt8(float4 a, float4 b) {
  u16x8 r;
  r[0] = f2bf(a.x); r[1] = f2bf(a.y); r[2] = f2bf(a.z); r[3] = f2bf(a.w);
  r[4] = f2bf(b.x); r[5] = f2bf(b.y); r[6] = f2bf(b.z); r[7] = f2bf(b.w);
  return r;
}

__device__ __forceinline__ void gl_lds16(const void* g, void* l) {
  __builtin_amdgcn_global_load_lds(
      (const __attribute__((address_space(1))) void*)g,
      (__attribute__((address_space(3))) void*)l, 16, 0, 0);
}

__device__ __forceinline__ bool find_expert(const int* cnt, int p0, int& eSel,
                                            int& realEnd) {
  int base = 0;
  for (int i = 0; i < NE9; i++) {
    int c = cnt[i];
    int pad = (c + 127) & ~127;
    if (p0 < base + pad) { eSel = i; realEnd = base + c; return p0 < base + c; }
    base += pad;
  }
  return false;
}

// ---------- init ----------
__global__ void init_kernel(int* __restrict__ cnt, int* __restrict__ fill) {
  int i = threadIdx.x;
  if (i < NE9) { cnt[i] = (i == NE) ? T_TOKENS : 0; fill[i] = 0; }
}

// ---------- zero out ----------
__global__ __launch_bounds__(256) void zero_kernel(float* __restrict__ p, int n) {
  int i = (blockIdx.x * 256 + threadIdx.x) * 4;
  if (i < n) *(float4*)(p + i) = make_float4(0.f, 0.f, 0.f, 0.f);
}

// ---------- fp32 -> bf16 (single source) ----------
__global__ __launch_bounds__(256) void cvt_kernel(const float* __restrict__ s,
                                                  unsigned short* __restrict__ d,
                                                  int n) {
  int i = (blockIdx.x * 256 + threadIdx.x) * 8;
  if (i >= n) return;
  float4 a = *(const float4*)(s + i);
  float4 b = *(const float4*)(s + i + 4);
  *(u16x8*)(d + i) = cvt8(a, b);
}

// ---------- fp32 -> bf16 (routed + shared into one 9-expert buffer) ----------
__global__ __launch_bounds__(256) void cvt2_kernel(const float* __restrict__ a,
                                                   const float* __restrict__ b,
                                                   unsigned short* __restrict__ d,
                                                   int na, int nb) {
  int i = (blockIdx.x * 256 + threadIdx.x) * 8;
  if (i >= na + nb) return;
  const float* src = (i < na) ? (a + i) : (b + (i - na));
  float4 va = *(const float4*)src;
  float4 vb = *(const float4*)(src + 4);
  *(u16x8*)(d + i) = cvt8(va, vb);
}

// ---------- gate ----------
__global__ __launch_bounds__(256) void gate_kernel(
    const float* __restrict__ x, const float* __restrict__ gw,
    const float* __restrict__ gb, int* __restrict__ cnt,
    int* __restrict__ topk_idx, float* __restrict__ topk_w) {
  const int wave = threadIdx.x >> 6;
  const int lane = threadIdx.x & 63;
  const int t = blockIdx.x * 4 + wave;
  if (t >= T_TOKENS) return;
  const float* xt = x + (size_t)t * DIMK;

  float p[NE];
#pragma unroll
  for (int e = 0; e < NE; e++) p[e] = 0.0f;
  for (int d = lane; d < DIMK; d += 64) {
    float xv = xt[d];
#pragma unroll
    for (int e = 0; e < NE; e++) p[e] += xv * gw[e * DIMK + d];
  }
#pragma unroll
  for (int e = 0; e < NE; e++) {
#pragma unroll
    for (int off = 32; off > 0; off >>= 1) p[e] += __shfl_xor(p[e], off, 64);
  }
  if (lane == 0) {
    float m = p[0];
#pragma unroll
    for (int e = 1; e < NE; e++) m = fmaxf(m, p[e]);
    float s[NE]; float den = 0.0f;
#pragma unroll
    for (int e = 0; e < NE; e++) { s[e] = expf(p[e] - m); den += s[e]; }
    float inv = 1.0f / den;
    float sc[NE], bi[NE];
#pragma unroll
    for (int e = 0; e < NE; e++) { sc[e] = s[e] * inv; bi[e] = sc[e] + gb[e]; }
    int i0 = 0; float b0 = bi[0];
#pragma unroll
    for (int e = 1; e < NE; e++) if (bi[e] > b0) { b0 = bi[e]; i0 = e; }
    int i1 = -1; float b1 = -1e30f;
#pragma unroll
    for (int e = 0; e < NE; e++) if (e != i0 && bi[e] > b1) { b1 = bi[e]; i1 = e; }
    topk_idx[t * 2 + 0] = i0;
    topk_idx[t * 2 + 1] = i1;
    topk_w[t * 2 + 0] = sc[i0];
    topk_w[t * 2 + 1] = sc[i1];
    atomicAdd(&cnt[i0], 1);
    atomicAdd(&cnt[i1], 1);
  }
}

// ---------- scatter: 3 entries per token (2 routed + shared e=8, w=1) ----------
__global__ __launch_bounds__(256) void scatter_kernel(
    const int* __restrict__ cnt, int* __restrict__ fill,
    const int* __restrict__ topk_idx, const float* __restrict__ topk_w,
    int* __restrict__ pair_tok, float* __restrict__ pair_w,
    int* __restrict__ pos) {
  int t = blockIdx.x * blockDim.x + threadIdx.x;
  if (t >= T_TOKENS) return;
  int offp[NE9];
  int o = 0;
#pragma unroll
  for (int e = 0; e < NE9; e++) { offp[e] = o; o += (cnt[e] + 127) & ~127; }
#pragma unroll
  for (int k = 0; k < 3; k++) {
    int e = (k < 2) ? topk_idx[t * 2 + k] : NE;
    float w = (k < 2) ? topk_w[t * 2 + k] : 1.0f;
    int po = atomicAdd(&fill[e], 1);
    int p = offp[e] + po;
    pair_tok[p] = t;
    pair_w[p] = w;
    pos[t * 3 + k] = p;
  }
}

// ---------- GEMM 1: H = silu(A@W1^T)*(A@W3^T), all 9 experts in one grid ----
// 128M x 64N block; 4 waves; triple-buffered LDS, counted-vmcnt pipeline.
template <bool BBF16>
__global__ __launch_bounds__(256) void h_mfma(
    const unsigned short* __restrict__ xb, const void* __restrict__ w1p,
    const void* __restrict__ w3p, const void* __restrict__ sw1p,
    const void* __restrict__ sw3p, const int* __restrict__ cnt,
    const int* __restrict__ pair_tok, unsigned short* __restrict__ H) {
  const int p0 = blockIdx.y * 128;
  int realEnd = 0, eSel = 0;
  if (!find_expert(cnt, p0, eSel, realEnd)) return;

  const int tid = threadIdx.x;
  const int lane = tid & 63;
  const int wv = tid >> 6;
  const int wm = (wv & 1) * 64, wn = (wv >> 1) * 32;
  const int lm = lane & 15, quad = lane >> 4;
  const int n0 = blockIdx.x * 64;

  const int srow = tid >> 2;
  const int skg = (tid & 3) * 8;

  int pa0 = p0 + srow, pa1 = p0 + srow + 64;
  int tok0 = pair_tok[pa0 < realEnd ? pa0 : realEnd - 1];
  int tok1 = pair_tok[pa1 < realEnd ? pa1 : realEnd - 1];
  const unsigned short* aSrc0 = xb + (size_t)tok0 * DIMK + skg;
  const unsigned short* aSrc1 = xb + (size_t)tok1 * DIMK + skg;

  __shared__ alignas(16) unsigned short As[3][128 * 32];
  __shared__ alignas(16) unsigned short B1s[3][64 * 32];
  __shared__ alignas(16) unsigned short B3s[3][64 * 32];

  f32x4 acc1[4][2] = {};
  f32x4 acc3[4][2] = {};

  auto compute = [&](int b) {
    bf16x8 af[4], b1r[2], b3r[2];
#pragma unroll
    for (int mi = 0; mi < 4; mi++)
      af[mi] = *(const bf16x8*)&As[b][(wm + mi * 16 + lm) * 32 + quad * 8];
#pragma unroll
    for (int ni = 0; ni < 2; ni++) {
      b1r[ni] = *(const bf16x8*)&B1s[b][(wn + ni * 16 + lm) * 32 + quad * 8];
      b3r[ni] = *(const bf16x8*)&B3s[b][(wn + ni * 16 + lm) * 32 + quad * 8];
    }
#pragma unroll
    for (int mi = 0; mi < 4; mi++) {
#pragma unroll
      for (int ni = 0; ni < 2; ni++) {
        acc1[mi][ni] = __builtin_amdgcn_mfma_f32_16x16x32_bf16(
            af[mi], b1r[ni], acc1[mi][ni], 0, 0, 0);
        acc3[mi][ni] = __builtin_amdgcn_mfma_f32_16x16x32_bf16(
            af[mi], b3r[ni], acc3[mi][ni], 0, 0, 0);
      }
    }
  };

  if constexpr (BBF16) {
    const size_t wOff = (size_t)eSel * INTER * DIMK;
    const unsigned short* b1Src =
        (const unsigned short*)w1p + wOff + (size_t)(n0 + srow) * DIMK + skg;
    const unsigned short* b3Src =
        (const unsigned short*)w3p + wOff + (size_t)(n0 + srow) * DIMK + skg;

    auto stage = [&](int j, int k0) {
      gl_lds16(aSrc0 + k0, &As[j][tid * 8]);
      gl_lds16(aSrc1 + k0, &As[j][2048 + tid * 8]);
      gl_lds16(b1Src + k0, &B1s[j][tid * 8]);
      gl_lds16(b3Src + k0, &B3s[j][tid * 8]);
    };

    stage(0, 0);
    stage(1, 32);
    int j = 0;
    for (int t = 0; t < 30; ++t) {  // NT = DIMK/32 = 32 tiles
      int j2 = j + 2; if (j2 >= 3) j2 -= 3;
      stage(j2, (t + 2) * 32);
      VM_WAIT(8);                   // oldest tile's 4 loads done; 8 stay in flight
      __builtin_amdgcn_s_barrier();
      SCHED_FENCE();
      compute(j);
      SCHED_FENCE();
      __builtin_amdgcn_s_barrier();
      j = (j == 2) ? 0 : j + 1;
    }
    VM_WAIT(4);
    __builtin_amdgcn_s_barrier();
    SCHED_FENCE();
    compute(j);
    j = (j == 2) ? 0 : j + 1;
    VM_WAIT(0);
    __builtin_amdgcn_s_barrier();
    SCHED_FENCE();
    compute(j);
  } else {
    const float* b1f = ((eSel < NE) ? (const float*)w1p + (size_t)eSel * INTER * DIMK
                                    : (const float*)sw1p) +
                       (size_t)(n0 + srow) * DIMK + skg;
    const float* b3f = ((eSel < NE) ? (const float*)w3p + (size_t)eSel * INTER * DIMK
                                    : (const float*)sw3p) +
                       (size_t)(n0 + srow) * DIMK + skg;
    for (int k0 = 0; k0 < DIMK; k0 += 32) {
      const float4* p1 = (const float4*)(b1f + k0);
      const float4* p3 = (const float4*)(b3f + k0);
      float4 a1 = p1[0], c1 = p1[1], a3 = p3[0], c3 = p3[1];
      u16x8 b1v = cvt8(a1, c1);
      u16x8 b3v = cvt8(a3, c3);
      __syncthreads();
      gl_lds16(aSrc0 + k0, &As[0][tid * 8]);
      gl_lds16(aSrc1 + k0, &As[0][2048 + tid * 8]);
      *(u16x8*)&B1s[0][tid * 8] = b1v;
      *(u16x8*)&B3s[0][tid * 8] = b3v;
      __syncthreads();
      compute(0);
    }
  }

#pragma unroll
  for (int mi = 0; mi < 4; mi++) {
#pragma unroll
    for (int r = 0; r < 4; r++) {
      int row = p0 + wm + mi * 16 + quad * 4 + r;
      if (row < realEnd) {
        unsigned short* hrow = H + (size_t)row * INTER + n0 + wn + lm;
#pragma unroll
        for (int ni = 0; ni < 2; ni++) {
          float v = silu_f(acc1[mi][ni][r]) * acc3[mi][ni][r];
          hrow[ni * 16] = f2bf(v);
        }
      }
    }
  }
}

// ---------- GEMM 2: R = H @ W2^T (128x128 block, 64x64/wave) ----------
template <bool BBF16, bool SCRATCH>
__global__ __launch_bounds__(256) void out_mfma(
    const unsigned short* __restrict__ H, const void* __restrict__ w2p,
    const void* __restrict__ sw2p, const int* __restrict__ cnt,
    const int* __restrict__ pair_tok, const float* __restrict__ pair_w,
    float* __restrict__ out, float* __restrict__ rout) {
  const int p0 = blockIdx.y * 128;
  int realEnd = 0, eSel = 0;
  if (!find_expert(cnt, p0, eSel, realEnd)) return;

  const int tid = threadIdx.x;
  const int lane = tid & 63;
  const int wv = tid >> 6;
  const int wm = (wv & 1) * 64, wn = (wv >> 1) * 64;
  const int lm = lane & 15, quad = lane >> 4;
  const int n0 = blockIdx.x * 128;

  const int srow = tid >> 2;
  const int skg = (tid & 3) * 8;

  const unsigned short* aSrc0 = H + (size_t)(p0 + srow) * INTER + skg;
  const unsigned short* aSrc1 = H + (size_t)(p0 + srow + 64) * INTER + skg;

  __shared__ alignas(16) unsigned short As[3][128 * 32];
  __shared__ alignas(16) unsigned short Bs[3][128 * 32];

  f32x4 acc[4][4] = {};

  auto compute = [&](int b) {
    bf16x8 af[4], bf[4];
#pragma unroll
    for (int mi = 0; mi < 4; mi++)
      af[mi] = *(const bf16x8*)&As[b][(wm + mi * 16 + lm) * 32 + quad * 8];
#pragma unroll
    for (int ni = 0; ni < 4; ni++)
      bf[ni] = *(const bf16x8*)&Bs[b][(wn + ni * 16 + lm) * 32 + quad * 8];
#pragma unroll
    for (int mi = 0; mi < 4; mi++) {
#pragma unroll
      for (int ni = 0; ni < 4; ni++) {
        acc[mi][ni] = __builtin_amdgcn_mfma_f32_16x16x32_bf16(
            af[mi], bf[ni], acc[mi][ni], 0, 0, 0);
      }
    }
  };

  if constexpr (BBF16) {
    const size_t wOff = (size_t)eSel * DIMK * INTER;
    const unsigned short* bSrc0 =
        (const unsigned short*)w2p + wOff + (size_t)(n0 + srow) * INTER + skg;
    const unsigned short* bSrc1 =
        (const unsigned short*)w2p + wOff + (size_t)(n0 + srow + 64) * INTER + skg;

    auto stage = [&](int j, int k0) {
      gl_lds16(aSrc0 + k0, &As[j][tid * 8]);
      gl_lds16(aSrc1 + k0, &As[j][2048 + tid * 8]);
      gl_lds16(bSrc0 + k0, &Bs[j][tid * 8]);
      gl_lds16(bSrc1 + k0, &Bs[j][2048 + tid * 8]);
    };

    stage(0, 0);
    stage(1, 32);
    int j = 0;
    for (int t = 0; t < 62; ++t) {  // NT = INTER/32 = 64 tiles
      int j2 = j + 2; if (j2 >= 3) j2 -= 3;
      stage(j2, (t + 2) * 32);
      VM_WAIT(8);
      __builtin_amdgcn_s_barrier();
      SCHED_FENCE();
      compute(j);
      SCHED_FENCE();
      __builtin_amdgcn_s_barrier();
      j = (j == 2) ? 0 : j + 1;
    }
    VM_WAIT(4);
    __builtin_amdgcn_s_barrier();
    SCHED_FENCE();
    compute(j);
    j = (j == 2) ? 0 : j + 1;
    VM_WAIT(0);
    __builtin_amdgcn_s_barrier();
    SCHED_FENCE();
    compute(j);
  } else {
    const float* bF0 = ((eSel < NE) ? (const float*)w2p + (size_t)eSel * DIMK * INTER
                                    : (const float*)sw2p) +
                       (size_t)(n0 + srow) * INTER + skg;
    const float* bF1 = bF0 + (size_t)64 * INTER;
    for (int k0 = 0; k0 < INTER; k0 += 32) {
      const float4* q0 = (const float4*)(bF0 + k0);
      const float4* q1 = (const float4*)(bF1 + k0);
      float4 a0 = q0[0], c0 = q0[1], a1 = q1[0], c1 = q1[1];
      u16x8 bv0 = cvt8(a0, c0);
      u16x8 bv1 = cvt8(a1, c1);
      __syncthreads();
      gl_lds16(aSrc0 + k0, &As[0][tid * 8]);
      gl_lds16(aSrc1 + k0, &As[0][2048 + tid * 8]);
      *(u16x8*)&Bs[0][tid * 8] = bv0;
      *(u16x8*)&Bs[0][2048 + tid * 8] = bv1;
      __syncthreads();
      compute(0);
    }
  }

#pragma unroll
  for (int mi = 0; mi < 4; mi++) {
#pragma unroll
    for (int r = 0; r < 4; r++) {
      int row = p0 + wm + mi * 16 + quad * 4 + r;
      if (row < realEnd) {
        if constexpr (SCRATCH) {
          float* rrow = rout + (size_t)row * DIMK + n0 + wn + lm;
#pragma unroll
          for (int ni = 0; ni < 4; ni++) rrow[ni * 16] = acc[mi][ni][r];
        } else {
          int tok = pair_tok[row];
          float wgt = pair_w[row];
          float* orow = out + (size_t)tok * DIMK + n0 + wn + lm;
#pragma unroll
          for (int ni = 0; ni < 4; ni++)
            atomicAdd(&orow[ni * 16], acc[mi][ni][r] * wgt);
        }
      }
    }
  }
}

// ---------- combine: out[t] = w0*R[q0] + w1*R[q1] + R[q2]  (pure write) ----
__global__ __launch_bounds__(256) void combine_kernel(
    const float* __restrict__ rt, const int* __restrict__ pos,
    const float* __restrict__ topk_w, float* __restrict__ out) {
  const int t = blockIdx.x;
  const int c = threadIdx.x * 4;
  const int q0 = pos[t * 3 + 0], q1 = pos[t * 3 + 1], q2 = pos[t * 3 + 2];
  const float w0 = topk_w[t * 2 + 0], w1 = topk_w[t * 2 + 1];
  float4 a = *(const float4*)(rt + (size_t)q0 * DIMK + c);
  float4 b = *(const float4*)(rt + (size_t)q1 * DIMK + c);
  float4 s = *(const float4*)(rt + (size_t)q2 * DIMK + c);
  float4 o;
  o.x = w0 * a.x + w1 * b.x + s.x;
  o.y = w0 * a.y + w1 * b.y + s.y;
  o.z = w0 * a.z + w1 * b.z + s.z;
  o.w = w0 * a.w + w1 * b.w + s.w;
  *(float4*)(out + (size_t)t * DIMK + c) = o;
}

// ---------- launch ----------
extern "C" void kernel_launch(void* const* d_in, const int* in_sizes, int n_in,
                              void* d_out, int out_size, void* d_ws, size_t ws_size,
                              hipStream_t stream) {
  const float* x   = (const float*)d_in[0];
  const float* gw  = (const float*)d_in[1];
  const float* gb  = (const float*)d_in[2];
  const float* w1  = (const float*)d_in[3];
  const float* w2  = (const float*)d_in[4];
  const float* w3  = (const float*)d_in[5];
  const float* sw1 = (const float*)d_in[6];
  const float* sw2 = (const float*)d_in[7];
  const float* sw3 = (const float*)d_in[8];
  float* out = (float*)d_out;
  (void)in_sizes; (void)n_in; (void)out_size;

  char* ws = (char*)d_ws;
  int* cnt = (int*)ws;                       // 16
  int* fill = cnt + 16;                      // 16
  int* topk_idx = fill + 16;                 // 2T
  float* topk_w = (float*)(topk_idx + 2 * T_TOKENS);
  int* pos = (int*)(topk_w + 2 * T_TOKENS);  // 3T
  int* pair_tok = pos + 3 * T_TOKENS;        // CAP9
  float* pair_w = (float*)(pair_tok + CAP9); // CAP9
  size_t off = (size_t)((char*)(pair_w + CAP9) - ws);
  off = (off + 255) & ~(size_t)255;
  unsigned short* H = (unsigned short*)(ws + off);
  off += (size_t)CAP9 * INTER * 2;           // 104.9 MB
  unsigned short* xb = (unsigned short*)(ws + off);
  off += (size_t)T_TOKENS * DIMK * 2;        // 16.8 MB

  const size_t nRW = (size_t)NE * INTER * DIMK;     // 16.78M elems (8 experts)
  const size_t nSW = (size_t)INTER * DIMK;          // 2.10M elems (shared)
  const size_t nW9 = (size_t)NE9 * INTER * DIMK;    // 18.87M elems
  const size_t avail = (ws_size > off) ? ws_size - off : 0;
  const size_t needRt = (size_t)CAP9 * DIMK * 4;    // 104.9 MB
  const size_t wA = 3 * nW9 * 2;                    // 113.2 MB (3 distinct)
  const size_t wB = 2 * nW9 * 2;                    // 75.5 MB (time-mux)

  bool USE_R = false, WA = false, WB = false;
  if (avail >= needRt + wA)      { USE_R = true; WA = true; }
  else if (avail >= needRt + wB) { USE_R = true; WB = true; }
  else if (avail >= wA)          { WA = true; }
  else if (avail >= wB)          { WB = true; }

  float* rt = nullptr;
  if (USE_R) { rt = (float*)(ws + off); off += needRt; }

  unsigned short *w1b9, *w3b9, *w2b9;
  if (WA) {
    unsigned short* Rg = (unsigned short*)(ws + off);
    w1b9 = Rg; w3b9 = Rg + nW9; w2b9 = Rg + 2 * nW9;
  } else if (WB) {
    unsigned short* Rg = (unsigned short*)(ws + off);
    w1b9 = Rg; w3b9 = Rg + nW9;  // phase 1
    w2b9 = Rg;                   // reuses region after h_mfma
  } else {
    w1b9 = w3b9 = w2b9 = nullptr;
  }
  const bool BF16W = (WA || WB);

  init_kernel<<<1, 64, 0, stream>>>(cnt, fill);
  gate_kernel<<<T_TOKENS / 4, 256, 0, stream>>>(x, gw, gb, cnt, topk_idx, topk_w);
  scatter_kernel<<<T_TOKENS / 256, 256, 0, stream>>>(cnt, fill, topk_idx, topk_w,
                                                     pair_tok, pair_w, pos);
  cvt_kernel<<<(T_TOKENS * DIMK) / 2048, 256, 0, stream>>>(x, xb, T_TOKENS * DIMK);

  const int cvt2_grid = (int)((nRW + nSW) / 2048);
  if (BF16W) {
    cvt2_kernel<<<cvt2_grid, 256, 0, stream>>>(w1, sw1, w1b9, (int)nRW, (int)nSW);
    cvt2_kernel<<<cvt2_grid, 256, 0, stream>>>(w3, sw3, w3b9, (int)nRW, (int)nSW);
    h_mfma<true><<<dim3(INTER / 64, CAP9 / 128), 256, 0, stream>>>(
        xb, w1b9, w3b9, nullptr, nullptr, cnt, pair_tok, H);
    cvt2_kernel<<<cvt2_grid, 256, 0, stream>>>(w2, sw2, w2b9, (int)nRW, (int)nSW);
    if (USE_R) {
      out_mfma<true, true><<<dim3(DIMK / 128, CAP9 / 128), 256, 0, stream>>>(
          H, w2b9, nullptr, cnt, pair_tok, pair_w, out, rt);
      combine_kernel<<<T_TOKENS, 256, 0, stream>>>(rt, pos, topk_w, out);
    } else {
      zero_kernel<<<(T_TOKENS * DIMK) / 1024, 256, 0, stream>>>(out,
                                                               T_TOKENS * DIMK);
      out_mfma<true, false><<<dim3(DIMK / 128, CAP9 / 128), 256, 0, stream>>>(
          H, w2b9, nullptr, cnt, pair_tok, pair_w, out, nullptr);
    }
  } else {
    zero_kernel<<<(T_TOKENS * DIMK) / 1024, 256, 0, stream>>>(out, T_TOKENS * DIMK);
    h_mfma<false><<<dim3(INTER / 64, CAP9 / 128), 256, 0, stream>>>(
        xb, w1, w3, sw1, sw3, cnt, pair_tok, H);
    out_mfma<false, false><<<dim3(DIMK / 128, CAP9 / 128), 256, 0, stream>>>(
        H, w2, sw2, cnt, pair_tok, pair_w, out, nullptr);
  }
}

// Round 6
// 1012.493 us; speedup vs baseline: 1.0424x; 1.0274x over previous
//
#include <hip/hip_runtime.h>
#include <hip/hip_bf16.h>
#include <math.h>

#define T_TOKENS 8192
#define DIMK     1024
#define INTER    2048
#define NE       8
#define NE9      9       // 8 routed + 1 shared (expert id 8)
#define CAP9     25600   // 2*T + 8*128 (routed padded) + T (shared)

typedef __attribute__((ext_vector_type(8))) short bf16x8;
typedef __attribute__((ext_vector_type(8))) unsigned short u16x8;
typedef __attribute__((ext_vector_type(4))) float f32x4;

#define VM_WAIT(N) asm volatile("s_waitcnt vmcnt(" #N ")" ::: "memory")
#define SCHED_FENCE() __builtin_amdgcn_sched_barrier(0)

__device__ __forceinline__ unsigned short f2bf(float f) {
  unsigned int u = __float_as_uint(f);
  unsigned int r = 0x7FFFu + ((u >> 16) & 1u);
  return (unsigned short)((u + r) >> 16);
}
__device__ __forceinline__ float silu_f(float v) { return v / (1.0f + expf(-v)); }

__device__ __forceinline__ u16x8 cvt8(float4 a, float4 b) {
  u16x8 r;
  r[0] = f2bf(a.x); r[1] = f2bf(a.y); r[2] = f2bf(a.z); r[3] = f2bf(a.w);
  r[4] = f2bf(b.x); r[5] = f2bf(b.y); r[6] = f2bf(b.z); r[7] = f2bf(b.w);
  return r;
}

__device__ __forceinline__ void gl_lds16(const void* g, void* l) {
  __builtin_amdgcn_global_load_lds(
      (const __attribute__((address_space(1))) void*)g,
      (__attribute__((address_space(3))) void*)l, 16, 0, 0);
}

__device__ __forceinline__ bool find_expert(const int* cnt, int p0, int& eSel,
                                            int& realEnd) {
  int base = 0;
  for (int i = 0; i < NE9; i++) {
    int c = cnt[i];
    int pad = (c + 127) & ~127;
    if (p0 < base + pad) { eSel = i; realEnd = base + c; return p0 < base + c; }
    base += pad;
  }
  return false;
}

// ---------- init ----------
__global__ void init_kernel(int* __restrict__ cnt, int* __restrict__ fill) {
  int i = threadIdx.x;
  if (i < NE9) { cnt[i] = (i == NE) ? T_TOKENS : 0; fill[i] = 0; }
}

// ---------- zero out ----------
__global__ __launch_bounds__(256) void zero_kernel(float* __restrict__ p, int n) {
  int i = (blockIdx.x * 256 + threadIdx.x) * 4;
  if (i < n) *(float4*)(p + i) = make_float4(0.f, 0.f, 0.f, 0.f);
}

// ---------- fp32 -> bf16 (single source) ----------
__global__ __launch_bounds__(256) void cvt_kernel(const float* __restrict__ s,
                                                  unsigned short* __restrict__ d,
                                                  int n) {
  int i = (blockIdx.x * 256 + threadIdx.x) * 8;
  if (i >= n) return;
  float4 a = *(const float4*)(s + i);
  float4 b = *(const float4*)(s + i + 4);
  *(u16x8*)(d + i) = cvt8(a, b);
}

// ---------- fp32 -> bf16 (routed + shared into one 9-expert buffer) ----------
__global__ __launch_bounds__(256) void cvt2_kernel(const float* __restrict__ a,
                                                   const float* __restrict__ b,
                                                   unsigned short* __restrict__ d,
                                                   int na, int nb) {
  int i = (blockIdx.x * 256 + threadIdx.x) * 8;
  if (i >= na + nb) return;
  const float* src = (i < na) ? (a + i) : (b + (i - na));
  float4 va = *(const float4*)src;
  float4 vb = *(const float4*)(src + 4);
  *(u16x8*)(d + i) = cvt8(va, vb);
}

// ---------- gate ----------
__global__ __launch_bounds__(256) void gate_kernel(
    const float* __restrict__ x, const float* __restrict__ gw,
    const float* __restrict__ gb, int* __restrict__ cnt,
    int* __restrict__ topk_idx, float* __restrict__ topk_w) {
  const int wave = threadIdx.x >> 6;
  const int lane = threadIdx.x & 63;
  const int t = blockIdx.x * 4 + wave;
  if (t >= T_TOKENS) return;
  const float* xt = x + (size_t)t * DIMK;

  float p[NE];
#pragma unroll
  for (int e = 0; e < NE; e++) p[e] = 0.0f;
  for (int d = lane; d < DIMK; d += 64) {
    float xv = xt[d];
#pragma unroll
    for (int e = 0; e < NE; e++) p[e] += xv * gw[e * DIMK + d];
  }
#pragma unroll
  for (int e = 0; e < NE; e++) {
#pragma unroll
    for (int off = 32; off > 0; off >>= 1) p[e] += __shfl_xor(p[e], off, 64);
  }
  if (lane == 0) {
    float m = p[0];
#pragma unroll
    for (int e = 1; e < NE; e++) m = fmaxf(m, p[e]);
    float s[NE]; float den = 0.0f;
#pragma unroll
    for (int e = 0; e < NE; e++) { s[e] = expf(p[e] - m); den += s[e]; }
    float inv = 1.0f / den;
    float sc[NE], bi[NE];
#pragma unroll
    for (int e = 0; e < NE; e++) { sc[e] = s[e] * inv; bi[e] = sc[e] + gb[e]; }
    int i0 = 0; float b0 = bi[0];
#pragma unroll
    for (int e = 1; e < NE; e++) if (bi[e] > b0) { b0 = bi[e]; i0 = e; }
    int i1 = -1; float b1 = -1e30f;
#pragma unroll
    for (int e = 0; e < NE; e++) if (e != i0 && bi[e] > b1) { b1 = bi[e]; i1 = e; }
    topk_idx[t * 2 + 0] = i0;
    topk_idx[t * 2 + 1] = i1;
    topk_w[t * 2 + 0] = sc[i0];
    topk_w[t * 2 + 1] = sc[i1];
    atomicAdd(&cnt[i0], 1);
    atomicAdd(&cnt[i1], 1);
  }
}

// ---------- scatter: 3 entries per token (2 routed + shared e=8, w=1) ----------
__global__ __launch_bounds__(256) void scatter_kernel(
    const int* __restrict__ cnt, int* __restrict__ fill,
    const int* __restrict__ topk_idx, const float* __restrict__ topk_w,
    int* __restrict__ pair_tok, float* __restrict__ pair_w,
    int* __restrict__ pos) {
  int t = blockIdx.x * blockDim.x + threadIdx.x;
  if (t >= T_TOKENS) return;
  int offp[NE9];
  int o = 0;
#pragma unroll
  for (int e = 0; e < NE9; e++) { offp[e] = o; o += (cnt[e] + 127) & ~127; }
#pragma unroll
  for (int k = 0; k < 3; k++) {
    int e = (k < 2) ? topk_idx[t * 2 + k] : NE;
    float w = (k < 2) ? topk_w[t * 2 + k] : 1.0f;
    int po = atomicAdd(&fill[e], 1);
    int p = offp[e] + po;
    pair_tok[p] = t;
    pair_w[p] = w;
    pos[t * 3 + k] = p;
  }
}

// ---------- GEMM 1: H = pair_w * silu(A@W1^T)*(A@W3^T), 9 experts ----------
// 128M x 128N block; 4 waves (2Mx2N, 64x64/wave per matrix); 2-buffer LDS,
// counted-vmcnt prefetch. Routing weight folded into H (GEMM2 is linear in H).
template <bool BBF16>
__global__ __launch_bounds__(256, 2) void h_mfma(
    const unsigned short* __restrict__ xb, const void* __restrict__ w1p,
    const void* __restrict__ w3p, const void* __restrict__ sw1p,
    const void* __restrict__ sw3p, const int* __restrict__ cnt,
    const int* __restrict__ pair_tok, const float* __restrict__ pair_w,
    unsigned short* __restrict__ H) {
  const int p0 = blockIdx.y * 128;
  int realEnd = 0, eSel = 0;
  if (!find_expert(cnt, p0, eSel, realEnd)) return;

  const int tid = threadIdx.x;
  const int lane = tid & 63;
  const int wv = tid >> 6;
  const int wm = (wv & 1) * 64, wn = (wv >> 1) * 64;
  const int lm = lane & 15, quad = lane >> 4;
  const int n0 = blockIdx.x * 128;

  const int srow = tid >> 2;
  const int skg = (tid & 3) * 8;

  int pa0 = p0 + srow, pa1 = p0 + srow + 64;
  int tok0 = pair_tok[pa0 < realEnd ? pa0 : realEnd - 1];
  int tok1 = pair_tok[pa1 < realEnd ? pa1 : realEnd - 1];
  const unsigned short* aSrc0 = xb + (size_t)tok0 * DIMK + skg;
  const unsigned short* aSrc1 = xb + (size_t)tok1 * DIMK + skg;

  __shared__ alignas(16) unsigned short As[2][128 * 32];
  __shared__ alignas(16) unsigned short B1s[2][128 * 32];
  __shared__ alignas(16) unsigned short B3s[2][128 * 32];

  f32x4 acc1[4][4] = {};
  f32x4 acc3[4][4] = {};

  auto compute = [&](int b) {
    bf16x8 af[4], b1r[4], b3r[4];
#pragma unroll
    for (int mi = 0; mi < 4; mi++)
      af[mi] = *(const bf16x8*)&As[b][(wm + mi * 16 + lm) * 32 + quad * 8];
#pragma unroll
    for (int ni = 0; ni < 4; ni++) {
      b1r[ni] = *(const bf16x8*)&B1s[b][(wn + ni * 16 + lm) * 32 + quad * 8];
      b3r[ni] = *(const bf16x8*)&B3s[b][(wn + ni * 16 + lm) * 32 + quad * 8];
    }
#pragma unroll
    for (int mi = 0; mi < 4; mi++) {
#pragma unroll
      for (int ni = 0; ni < 4; ni++) {
        acc1[mi][ni] = __builtin_amdgcn_mfma_f32_16x16x32_bf16(
            af[mi], b1r[ni], acc1[mi][ni], 0, 0, 0);
        acc3[mi][ni] = __builtin_amdgcn_mfma_f32_16x16x32_bf16(
            af[mi], b3r[ni], acc3[mi][ni], 0, 0, 0);
      }
    }
  };

  if constexpr (BBF16) {
    const size_t wOff = (size_t)eSel * INTER * DIMK;
    const unsigned short* b1Src0 =
        (const unsigned short*)w1p + wOff + (size_t)(n0 + srow) * DIMK + skg;
    const unsigned short* b1Src1 = b1Src0 + (size_t)64 * DIMK;
    const unsigned short* b3Src0 =
        (const unsigned short*)w3p + wOff + (size_t)(n0 + srow) * DIMK + skg;
    const unsigned short* b3Src1 = b3Src0 + (size_t)64 * DIMK;

    auto stage = [&](int j, int k0) {
      gl_lds16(aSrc0 + k0, &As[j][tid * 8]);
      gl_lds16(aSrc1 + k0, &As[j][2048 + tid * 8]);
      gl_lds16(b1Src0 + k0, &B1s[j][tid * 8]);
      gl_lds16(b1Src1 + k0, &B1s[j][2048 + tid * 8]);
      gl_lds16(b3Src0 + k0, &B3s[j][tid * 8]);
      gl_lds16(b3Src1 + k0, &B3s[j][2048 + tid * 8]);
    };

    stage(0, 0);
    int cur = 0;
    for (int t = 0; t < 31; ++t) {  // NT = DIMK/32 = 32 tiles
      stage(cur ^ 1, (t + 1) * 32);
      VM_WAIT(6);                   // cur's 6 loads done; 6 stay in flight
      __builtin_amdgcn_s_barrier();
      SCHED_FENCE();
      compute(cur);
      SCHED_FENCE();
      __builtin_amdgcn_s_barrier();
      cur ^= 1;
    }
    VM_WAIT(0);
    __builtin_amdgcn_s_barrier();
    SCHED_FENCE();
    compute(cur);
  } else {
    const float* b1f = ((eSel < NE) ? (const float*)w1p + (size_t)eSel * INTER * DIMK
                                    : (const float*)sw1p) +
                       (size_t)(n0 + srow) * DIMK + skg;
    const float* b3f = ((eSel < NE) ? (const float*)w3p + (size_t)eSel * INTER * DIMK
                                    : (const float*)sw3p) +
                       (size_t)(n0 + srow) * DIMK + skg;
    const float* b1g = b1f + (size_t)64 * DIMK;
    const float* b3g = b3f + (size_t)64 * DIMK;
    for (int k0 = 0; k0 < DIMK; k0 += 32) {
      const float4* p1 = (const float4*)(b1f + k0);
      const float4* q1 = (const float4*)(b1g + k0);
      const float4* p3 = (const float4*)(b3f + k0);
      const float4* q3 = (const float4*)(b3g + k0);
      u16x8 v1a = cvt8(p1[0], p1[1]);
      u16x8 v1b = cvt8(q1[0], q1[1]);
      u16x8 v3a = cvt8(p3[0], p3[1]);
      u16x8 v3b = cvt8(q3[0], q3[1]);
      __syncthreads();
      gl_lds16(aSrc0 + k0, &As[0][tid * 8]);
      gl_lds16(aSrc1 + k0, &As[0][2048 + tid * 8]);
      *(u16x8*)&B1s[0][tid * 8] = v1a;
      *(u16x8*)&B1s[0][2048 + tid * 8] = v1b;
      *(u16x8*)&B3s[0][tid * 8] = v3a;
      *(u16x8*)&B3s[0][2048 + tid * 8] = v3b;
      __syncthreads();
      compute(0);
    }
  }

#pragma unroll
  for (int mi = 0; mi < 4; mi++) {
#pragma unroll
    for (int r = 0; r < 4; r++) {
      int row = p0 + wm + mi * 16 + quad * 4 + r;
      if (row < realEnd) {
        float pw = pair_w[row];
        unsigned short* hrow = H + (size_t)row * INTER + n0 + wn + lm;
#pragma unroll
        for (int ni = 0; ni < 4; ni++) {
          float v = silu_f(acc1[mi][ni][r]) * acc3[mi][ni][r] * pw;
          hrow[ni * 16] = f2bf(v);
        }
      }
    }
  }
}

// ---------- GEMM 2: R = H @ W2^T (128x128 block, 64x64/wave) ----------
template <bool BBF16, bool SCRATCH>
__global__ __launch_bounds__(256) void out_mfma(
    const unsigned short* __restrict__ H, const void* __restrict__ w2p,
    const void* __restrict__ sw2p, const int* __restrict__ cnt,
    const int* __restrict__ pair_tok, float* __restrict__ out,
    float* __restrict__ rout) {
  const int p0 = blockIdx.y * 128;
  int realEnd = 0, eSel = 0;
  if (!find_expert(cnt, p0, eSel, realEnd)) return;

  const int tid = threadIdx.x;
  const int lane = tid & 63;
  const int wv = tid >> 6;
  const int wm = (wv & 1) * 64, wn = (wv >> 1) * 64;
  const int lm = lane & 15, quad = lane >> 4;
  const int n0 = blockIdx.x * 128;

  const int srow = tid >> 2;
  const int skg = (tid & 3) * 8;

  const unsigned short* aSrc0 = H + (size_t)(p0 + srow) * INTER + skg;
  const unsigned short* aSrc1 = H + (size_t)(p0 + srow + 64) * INTER + skg;

  __shared__ alignas(16) unsigned short As[3][128 * 32];
  __shared__ alignas(16) unsigned short Bs[3][128 * 32];

  f32x4 acc[4][4] = {};

  auto compute = [&](int b) {
    bf16x8 af[4], bf[4];
#pragma unroll
    for (int mi = 0; mi < 4; mi++)
      af[mi] = *(const bf16x8*)&As[b][(wm + mi * 16 + lm) * 32 + quad * 8];
#pragma unroll
    for (int ni = 0; ni < 4; ni++)
      bf[ni] = *(const bf16x8*)&Bs[b][(wn + ni * 16 + lm) * 32 + quad * 8];
#pragma unroll
    for (int mi = 0; mi < 4; mi++) {
#pragma unroll
      for (int ni = 0; ni < 4; ni++) {
        acc[mi][ni] = __builtin_amdgcn_mfma_f32_16x16x32_bf16(
            af[mi], bf[ni], acc[mi][ni], 0, 0, 0);
      }
    }
  };

  if constexpr (BBF16) {
    const size_t wOff = (size_t)eSel * DIMK * INTER;
    const unsigned short* bSrc0 =
        (const unsigned short*)w2p + wOff + (size_t)(n0 + srow) * INTER + skg;
    const unsigned short* bSrc1 =
        (const unsigned short*)w2p + wOff + (size_t)(n0 + srow + 64) * INTER + skg;

    auto stage = [&](int j, int k0) {
      gl_lds16(aSrc0 + k0, &As[j][tid * 8]);
      gl_lds16(aSrc1 + k0, &As[j][2048 + tid * 8]);
      gl_lds16(bSrc0 + k0, &Bs[j][tid * 8]);
      gl_lds16(bSrc1 + k0, &Bs[j][2048 + tid * 8]);
    };

    stage(0, 0);
    stage(1, 32);
    int j = 0;
    for (int t = 0; t < 62; ++t) {  // NT = INTER/32 = 64 tiles
      int j2 = j + 2; if (j2 >= 3) j2 -= 3;
      stage(j2, (t + 2) * 32);
      VM_WAIT(8);
      __builtin_amdgcn_s_barrier();
      SCHED_FENCE();
      compute(j);
      SCHED_FENCE();
      __builtin_amdgcn_s_barrier();
      j = (j == 2) ? 0 : j + 1;
    }
    VM_WAIT(4);
    __builtin_amdgcn_s_barrier();
    SCHED_FENCE();
    compute(j);
    j = (j == 2) ? 0 : j + 1;
    VM_WAIT(0);
    __builtin_amdgcn_s_barrier();
    SCHED_FENCE();
    compute(j);
  } else {
    const float* bF0 = ((eSel < NE) ? (const float*)w2p + (size_t)eSel * DIMK * INTER
                                    : (const float*)sw2p) +
                       (size_t)(n0 + srow) * INTER + skg;
    const float* bF1 = bF0 + (size_t)64 * INTER;
    for (int k0 = 0; k0 < INTER; k0 += 32) {
      const float4* q0 = (const float4*)(bF0 + k0);
      const float4* q1 = (const float4*)(bF1 + k0);
      u16x8 bv0 = cvt8(q0[0], q0[1]);
      u16x8 bv1 = cvt8(q1[0], q1[1]);
      __syncthreads();
      gl_lds16(aSrc0 + k0, &As[0][tid * 8]);
      gl_lds16(aSrc1 + k0, &As[0][2048 + tid * 8]);
      *(u16x8*)&Bs[0][tid * 8] = bv0;
      *(u16x8*)&Bs[0][2048 + tid * 8] = bv1;
      __syncthreads();
      compute(0);
    }
  }

#pragma unroll
  for (int mi = 0; mi < 4; mi++) {
#pragma unroll
    for (int r = 0; r < 4; r++) {
      int row = p0 + wm + mi * 16 + quad * 4 + r;
      if (row < realEnd) {
        if constexpr (SCRATCH) {
          float* rrow = rout + (size_t)row * DIMK + n0 + wn + lm;
#pragma unroll
          for (int ni = 0; ni < 4; ni++) rrow[ni * 16] = acc[mi][ni][r];
        } else {
          int tok = pair_tok[row];
          float* orow = out + (size_t)tok * DIMK + n0 + wn + lm;
#pragma unroll
          for (int ni = 0; ni < 4; ni++)
            atomicAdd(&orow[ni * 16], acc[mi][ni][r]);
        }
      }
    }
  }
}

// ---------- combine: out[t] = R[q0] + R[q1] + R[q2]  (weights already in H) --
__global__ __launch_bounds__(256) void combine_kernel(
    const float* __restrict__ rt, const int* __restrict__ pos,
    float* __restrict__ out) {
  const int t = blockIdx.x;
  const int c = threadIdx.x * 4;
  const int q0 = pos[t * 3 + 0], q1 = pos[t * 3 + 1], q2 = pos[t * 3 + 2];
  float4 a = *(const float4*)(rt + (size_t)q0 * DIMK + c);
  float4 b = *(const float4*)(rt + (size_t)q1 * DIMK + c);
  float4 s = *(const float4*)(rt + (size_t)q2 * DIMK + c);
  float4 o;
  o.x = a.x + b.x + s.x;
  o.y = a.y + b.y + s.y;
  o.z = a.z + b.z + s.z;
  o.w = a.w + b.w + s.w;
  *(float4*)(out + (size_t)t * DIMK + c) = o;
}

// ---------- launch ----------
extern "C" void kernel_launch(void* const* d_in, const int* in_sizes, int n_in,
                              void* d_out, int out_size, void* d_ws, size_t ws_size,
                              hipStream_t stream) {
  const float* x   = (const float*)d_in[0];
  const float* gw  = (const float*)d_in[1];
  const float* gb  = (const float*)d_in[2];
  const float* w1  = (const float*)d_in[3];
  const float* w2  = (const float*)d_in[4];
  const float* w3  = (const float*)d_in[5];
  const float* sw1 = (const float*)d_in[6];
  const float* sw2 = (const float*)d_in[7];
  const float* sw3 = (const float*)d_in[8];
  float* out = (float*)d_out;
  (void)in_sizes; (void)n_in; (void)out_size;

  char* ws = (char*)d_ws;
  int* cnt = (int*)ws;                       // 16
  int* fill = cnt + 16;                      // 16
  int* topk_idx = fill + 16;                 // 2T
  float* topk_w = (float*)(topk_idx + 2 * T_TOKENS);
  int* pos = (int*)(topk_w + 2 * T_TOKENS);  // 3T
  int* pair_tok = pos + 3 * T_TOKENS;        // CAP9
  float* pair_w = (float*)(pair_tok + CAP9); // CAP9
  size_t off = (size_t)((char*)(pair_w + CAP9) - ws);
  off = (off + 255) & ~(size_t)255;
  unsigned short* H = (unsigned short*)(ws + off);
  off += (size_t)CAP9 * INTER * 2;           // 104.9 MB
  unsigned short* xb = (unsigned short*)(ws + off);
  off += (size_t)T_TOKENS * DIMK * 2;        // 16.8 MB

  const size_t nRW = (size_t)NE * INTER * DIMK;     // 16.78M elems (8 experts)
  const size_t nSW = (size_t)INTER * DIMK;          // 2.10M elems (shared)
  const size_t nW9 = (size_t)NE9 * INTER * DIMK;    // 18.87M elems
  const size_t avail = (ws_size > off) ? ws_size - off : 0;
  const size_t needRt = (size_t)CAP9 * DIMK * 4;    // 104.9 MB
  const size_t wA = 3 * nW9 * 2;                    // 113.2 MB (3 distinct)
  const size_t wB = 2 * nW9 * 2;                    // 75.5 MB (time-mux)

  bool USE_R = false, WA = false, WB = false;
  if (avail >= needRt + wA)      { USE_R = true; WA = true; }
  else if (avail >= needRt + wB) { USE_R = true; WB = true; }
  else if (avail >= wA)          { WA = true; }
  else if (avail >= wB)          { WB = true; }

  float* rt = nullptr;
  if (USE_R) { rt = (float*)(ws + off); off += needRt; }

  unsigned short *w1b9, *w3b9, *w2b9;
  if (WA) {
    unsigned short* Rg = (unsigned short*)(ws + off);
    w1b9 = Rg; w3b9 = Rg + nW9; w2b9 = Rg + 2 * nW9;
  } else if (WB) {
    unsigned short* Rg = (unsigned short*)(ws + off);
    w1b9 = Rg; w3b9 = Rg + nW9;  // phase 1
    w2b9 = Rg;                   // reuses region after h_mfma
  } else {
    w1b9 = w3b9 = w2b9 = nullptr;
  }
  const bool BF16W = (WA || WB);

  init_kernel<<<1, 64, 0, stream>>>(cnt, fill);
  gate_kernel<<<T_TOKENS / 4, 256, 0, stream>>>(x, gw, gb, cnt, topk_idx, topk_w);
  scatter_kernel<<<T_TOKENS / 256, 256, 0, stream>>>(cnt, fill, topk_idx, topk_w,
                                                     pair_tok, pair_w, pos);
  cvt_kernel<<<(T_TOKENS * DIMK) / 2048, 256, 0, stream>>>(x, xb, T_TOKENS * DIMK);

  const int cvt2_grid = (int)((nRW + nSW) / 2048);
  if (BF16W) {
    cvt2_kernel<<<cvt2_grid, 256, 0, stream>>>(w1, sw1, w1b9, (int)nRW, (int)nSW);
    cvt2_kernel<<<cvt2_grid, 256, 0, stream>>>(w3, sw3, w3b9, (int)nRW, (int)nSW);
    h_mfma<true><<<dim3(INTER / 128, CAP9 / 128), 256, 0, stream>>>(
        xb, w1b9, w3b9, nullptr, nullptr, cnt, pair_tok, pair_w, H);
    cvt2_kernel<<<cvt2_grid, 256, 0, stream>>>(w2, sw2, w2b9, (int)nRW, (int)nSW);
    if (USE_R) {
      out_mfma<true, true><<<dim3(DIMK / 128, CAP9 / 128), 256, 0, stream>>>(
          H, w2b9, nullptr, cnt, pair_tok, out, rt);
      combine_kernel<<<T_TOKENS, 256, 0, stream>>>(rt, pos, out);
    } else {
      zero_kernel<<<(T_TOKENS * DIMK) / 1024, 256, 0, stream>>>(out,
                                                               T_TOKENS * DIMK);
      out_mfma<true, false><<<dim3(DIMK / 128, CAP9 / 128), 256, 0, stream>>>(
          H, w2b9, nullptr, cnt, pair_tok, out, nullptr);
    }
  } else {
    zero_kernel<<<(T_TOKENS * DIMK) / 1024, 256, 0, stream>>>(out, T_TOKENS * DIMK);
    h_mfma<false><<<dim3(INTER / 128, CAP9 / 128), 256, 0, stream>>>(
        xb, w1, w3, sw1, sw3, cnt, pair_tok, pair_w, H);
    out_mfma<false, false><<<dim3(DIMK / 128, CAP9 / 128), 256, 0, stream>>>(
        H, w2, sw2, cnt, pair_tok, out, nullptr);
  }
}